// Round 9
// baseline (880.550 us; speedup 1.0000x reference)
//
#include <hip/hip_runtime.h>

typedef __attribute__((ext_vector_type(8))) short short8;
typedef __attribute__((ext_vector_type(4))) float f32x4;

// ---------- helpers ----------
__device__ __forceinline__ unsigned short f2bf(float f) {
    union { float f; unsigned int u; } v; v.f = f;
    unsigned int u = v.u;
    unsigned int r = (u + 0x7FFFu + ((u >> 16) & 1u)) >> 16;
    return (unsigned short)r;
}
__device__ __forceinline__ float bf2f(unsigned short u) {
    union { unsigned int u; float f; } v; v.u = ((unsigned int)u) << 16;
    return v.f;
}
__device__ __forceinline__ void load_lds16(const void* g, void* l) {
    __builtin_amdgcn_global_load_lds(
        (const __attribute__((address_space(1))) void*)g,
        (__attribute__((address_space(3))) void*)l, 16, 0, 0);
}
#define BAR() asm volatile("s_barrier" ::: "memory")
#define WAITV(n) asm volatile("s_waitcnt vmcnt(" #n ")" ::: "memory")

// LDS swizzle (R3/R4, measured 0 conflicts): XOR row&7 (bits 7-9 at 128B row
// stride) into the 16B-slot index (bits 4-6). Involution on 16B chunks.
__device__ __forceinline__ int swz(int o) { return o ^ ((o >> 3) & 0x70); }

// ---------- fp32 -> bf16 convert ----------
__global__ __launch_bounds__(256) void conv_bf16(const float* __restrict__ in,
                                                 unsigned short* __restrict__ out, int n4) {
    int i = blockIdx.x * 256 + threadIdx.x;
    if (i >= n4) return;
    float4 v = ((const float4*)in)[i];
    ushort4 o;
    o.x = f2bf(v.x); o.y = f2bf(v.y); o.z = f2bf(v.z); o.w = f2bf(v.w);
    ((ushort4*)out)[i] = o;
}

// ---------- 256x256 8-phase GEMM (R4/R8, best measured, 0 conflicts) ----------
template <bool OUT_BF16>
__global__ __launch_bounds__(512, 2) void gemm256(const unsigned short* __restrict__ A,
                                                  const unsigned short* __restrict__ B,
                                                  void* __restrict__ Cv,
                                                  int M, int N, int K, int NBN) {
    __shared__ __align__(16) char smem[131072];
    const int tid = threadIdx.x;
    const int lane = tid & 63, wv = tid >> 6;
    const int wm = wv >> 2, wn = wv & 3;
    const int fr = lane & 15, fo = (lane >> 4) * 8;

    // bijective XCD swizzle (m204)
    const int nwg = gridDim.x, bid = blockIdx.x;
    const int q = nwg >> 3, r = nwg & 7, xcd = bid & 7, lid = bid >> 3;
    const int wg = (xcd < r ? xcd * (q + 1) : r * (q + 1) + (xcd - r) * q) + lid;
    const int bm = wg / NBN, bn = wg % NBN;

    const unsigned short* gA = A + (size_t)bm * 256 * K;
    const unsigned short* gB = B + (size_t)bn * 256 * K;

    // staging geometry: linear LDS dest o -> global element at swz(o)
    int srow[2][2], scol[2][2];
#pragma unroll
    for (int h = 0; h < 2; ++h)
#pragma unroll
        for (int rr = 0; rr < 2; ++rr) {
            int o = h * 16384 + rr * 8192 + tid * 16;
            int osw = swz(o);
            srow[h][rr] = osw >> 7;
            scol[h][rr] = (osw & 127) >> 1;
        }

    f32x4 acc[8][4] = {};
    short8 a[4][2], b[4][2];

    auto STAGE = [&](const unsigned short* g, int regionBase, int h, int t) {
#pragma unroll
        for (int rr = 0; rr < 2; ++rr)
            load_lds16(g + (size_t)srow[h][rr] * K + t * 64 + scol[h][rr],
                       smem + regionBase + h * 16384 + rr * 8192 + tid * 16);
    };
    auto RDA = [&](int bufBase, int mh) {
#pragma unroll
        for (int mf = 0; mf < 4; ++mf)
#pragma unroll
            for (int ks = 0; ks < 2; ++ks) {
                int o = swz((wm * 128 + mh * 64 + mf * 16 + fr) * 128 + (ks * 32 + fo) * 2);
                a[mf][ks] = *(const short8*)(smem + bufBase + o);
            }
    };
    auto RDB = [&](int bufBase, int nh) {
#pragma unroll
        for (int jj = 0; jj < 2; ++jj)
#pragma unroll
            for (int ks = 0; ks < 2; ++ks) {
                int o = swz((wn * 64 + (nh * 2 + jj) * 16 + fr) * 128 + (ks * 32 + fo) * 2);
                b[nh * 2 + jj][ks] = *(const short8*)(smem + bufBase + 32768 + o);
            }
    };
    auto MM = [&](int mh, int nh) {
        __builtin_amdgcn_s_setprio(1);
#pragma unroll
        for (int mf = 0; mf < 4; ++mf)
#pragma unroll
            for (int jj = 0; jj < 2; ++jj)
#pragma unroll
                for (int ks = 0; ks < 2; ++ks)
                    acc[mh * 4 + mf][nh * 2 + jj] = __builtin_amdgcn_mfma_f32_16x16x32_bf16(
                        a[mf][ks], b[nh * 2 + jj][ks], acc[mh * 4 + mf][nh * 2 + jj], 0, 0, 0);
        __builtin_amdgcn_s_setprio(0);
    };

    const int A0 = 0, B0 = 32768, A1 = 65536, B1 = 98304;

    // prologue: t0 (A,B) -> buf0; t1 (B,A) -> buf1. 16 loads.
    STAGE(gA, A0, 0, 0); STAGE(gA, A0, 1, 0);
    STAGE(gB, B0, 0, 0); STAGE(gB, B0, 1, 0);
    STAGE(gB, B1, 0, 1); STAGE(gB, B1, 1, 1);
    STAGE(gA, A1, 0, 1); STAGE(gA, A1, 1, 1);
    WAITV(8);
    BAR();
    RDA(A0, 0);
    RDB(A0, 0);

    const int NIT = K >> 7;  // K/128
    for (int i = 0; i < NIT; ++i) {
        const bool last = (i == NIT - 1);
        const int t2 = 2 * i + 2, t3 = 2 * i + 3;
        // P1
        RDB(A0, 1);
        MM(0, 0);
        if (i > 0) STAGE(gA, A1, 1, 2 * i + 1);
        BAR();
        // P2
        MM(0, 1);
        RDA(A0, 1);
        BAR();
        // P3
        MM(1, 1);
        if (!last) {
            STAGE(gB, B0, 0, t2);
            WAITV(2);
        } else {
            WAITV(0);
        }
        BAR();
        // P4
        MM(1, 0);
        RDA(A1, 0); RDB(A1, 0);
        if (!last) { STAGE(gB, B0, 1, t2); STAGE(gA, A0, 0, t2); }
        BAR();
        // P5
        RDB(A1, 1);
        MM(0, 0);
        if (!last) STAGE(gA, A0, 1, t2);
        BAR();
        // P6
        MM(0, 1);
        RDA(A1, 1);
        BAR();
        // P7
        MM(1, 1);
        if (!last) {
            STAGE(gB, B1, 0, t3);
            WAITV(2);
        }
        BAR();
        // P8
        MM(1, 0);
        if (!last) {
            RDA(A0, 0); RDB(A0, 0);
            STAGE(gB, B1, 1, t3); STAGE(gA, A1, 0, t3);
        }
        BAR();
    }

    // epilogue
    const size_t row0 = (size_t)bm * 256 + wm * 128 + ((lane >> 4) << 2);
    const int col0 = bn * 256 + wn * 64 + fr;
#pragma unroll
    for (int mf = 0; mf < 8; ++mf)
#pragma unroll
        for (int nf = 0; nf < 4; ++nf)
#pragma unroll
            for (int j = 0; j < 4; ++j) {
                size_t idx = (row0 + mf * 16 + j) * (size_t)N + col0 + nf * 16;
                if (OUT_BF16) ((unsigned short*)Cv)[idx] = f2bf(acc[mf][nf][j]);
                else          ((float*)Cv)[idx] = acc[mf][nf][j];
            }
}

// ---------- RoPE (interleaved, first 64 dims) + repack q,k -> [b,h,s,d] ----------
__global__ __launch_bounds__(256) void rope_repack(const unsigned short* __restrict__ qkv,
                                                   const int* __restrict__ positions,
                                                   unsigned short* __restrict__ qp,
                                                   unsigned short* __restrict__ kp) {
    int r = blockIdx.x * 4 + (threadIdx.x >> 6);   // (b,s,h) row, 0..65535
    int h = r & 15, s = (r >> 4) & 2047, b = r >> 15;
    int d = (threadIdx.x & 63) * 4;
    const unsigned short* src = qkv + (size_t)(b * 2048 + s) * 12288 + h * 256 + d;
    ushort4 q = *(const ushort4*)src;
    ushort4 k = *(const ushort4*)(src + 4096);
    if (d < 64) {
        float pos = (float)positions[s];
        const float LF = 0.4152410118609203f;      // log2(10000)/32
        float i0 = (float)(d >> 1);
        float a0 = pos * exp2f(-i0 * LF);
        float a1 = pos * exp2f(-(i0 + 1.0f) * LF);
        float c0 = cosf(a0), s0 = sinf(a0), c1 = cosf(a1), s1 = sinf(a1);
        float qx = bf2f(q.x), qy = bf2f(q.y), qz = bf2f(q.z), qw = bf2f(q.w);
        q.x = f2bf(qx * c0 - qy * s0); q.y = f2bf(qx * s0 + qy * c0);
        q.z = f2bf(qz * c1 - qw * s1); q.w = f2bf(qz * s1 + qw * c1);
        float kx = bf2f(k.x), ky = bf2f(k.y), kz = bf2f(k.z), kw = bf2f(k.w);
        k.x = f2bf(kx * c0 - ky * s0); k.y = f2bf(kx * s0 + ky * c0);
        k.z = f2bf(kz * c1 - kw * s1); k.w = f2bf(kz * s1 + kw * c1);
    }
    size_t dst = ((size_t)((b * 16 + h) * 2048 + s)) * 256 + d;
    *(ushort4*)&qp[dst] = q;
    *(ushort4*)&kp[dst] = k;
}

// ---------- V transpose -> [b,h,d,s] ----------
__global__ __launch_bounds__(256) void v_transpose(const unsigned short* __restrict__ qkv,
                                                   unsigned short* __restrict__ vt) {
    int bid = blockIdx.x;
    int dt = bid & 3, st = (bid >> 2) & 31, bh = bid >> 7;
    int b = bh >> 4, h = bh & 15;
    __shared__ unsigned short t[64][72];
    int tid = threadIdx.x;
#pragma unroll
    for (int rep = 0; rep < 16; ++rep) {
        int idx = rep * 256 + tid;
        int r = idx >> 6, c = idx & 63;   // r: s-offset, c: d-offset
        t[r][c] = qkv[(size_t)(b * 2048 + st * 64 + r) * 12288 + 8192 + h * 256 + dt * 64 + c];
    }
    __syncthreads();
#pragma unroll
    for (int rep = 0; rep < 16; ++rep) {
        int idx = rep * 256 + tid;
        int r = idx >> 6, c = idx & 63;   // r: d-offset, c: s-offset
        vt[(size_t)(bh * 256 + dt * 64 + r) * 2048 + st * 64 + c] = t[c][r];
    }
}

// ---------- flash attention (causal), 4 waves x 16 q-rows, KV tile 32 ----------
// Double-buffered staging (R9): stage tile t+1 into buf[(t+1)&1] BEFORE
// computing tile t; vmcnt(8) waits only tile t's 8 loads (t+1's stay in
// flight across the compute phase). End-of-compute barrier retires reads of
// buf[t&1] before next iteration's stage overwrites it (t+2 -> same buf).
// K/V swizzles + defer-max unchanged from R8 (verified, absmax 0.03125).
// LDS: 2x(16K+16K) + 4K = 68 KB -> 2 blocks/CU.
__global__ __launch_bounds__(256) void attn_fwd(const unsigned short* __restrict__ Qp,
                                                const unsigned short* __restrict__ Kp,
                                                const unsigned short* __restrict__ Vt,
                                                unsigned short* __restrict__ Oa) {
    __shared__ __align__(16) unsigned short Ks[2][32 * 256];
    __shared__ __align__(16) unsigned short Vs[2][256 * 32];
    __shared__ __align__(16) unsigned short Ps[4][16 * 32];
    const int tid = threadIdx.x, lane = tid & 63, wv = tid >> 6;
    const int bh = blockIdx.x, qt = blockIdx.y;
    const int fr = lane & 15, fo = (lane >> 4) * 8;
    const unsigned short* Qb = Qp + (size_t)bh * 2048 * 256;
    const unsigned short* Kb = Kp + (size_t)bh * 2048 * 256;
    const unsigned short* Vb = Vt + (size_t)bh * 256 * 2048;
    const int qbase = qt * 64 + wv * 16;

    short8 qf[8];
#pragma unroll
    for (int c = 0; c < 8; ++c)
        qf[c] = *(const short8*)&Qb[(size_t)(qbase + fr) * 256 + c * 32 + fo];

    f32x4 o_acc[16] = {};
    float m_run[4] = {-1e30f, -1e30f, -1e30f, -1e30f};
    float l_run[4] = {0.f, 0.f, 0.f, 0.f};

    auto STAGE_T = [&](int t, int bsel) {
        const int kv0 = t * 32;
#pragma unroll
        for (int i = 0; i < 4; ++i) {
            int ob = (wv * 4 + i) * 1024 + lane * 16;          // dest byte off
            int osw = ob ^ ((ob >> 5) & 0x70);
            int row = kv0 + (ob >> 9);
            load_lds16(&Kb[(size_t)row * 256 + ((osw & 511) >> 1)],
                       (char*)Ks[bsel] + (wv * 4 + i) * 1024);
        }
#pragma unroll
        for (int i = 0; i < 4; ++i) {
            int ob = (wv * 4 + i) * 1024 + lane * 16;
            int osw = ob ^ ((((ob >> 6) ^ (ob >> 8)) & 3) << 4);
            int drow = ob >> 6;
            load_lds16(&Vb[(size_t)drow * 2048 + kv0 + ((osw & 63) >> 1)],
                       (char*)Vs[bsel] + (wv * 4 + i) * 1024);
        }
    };

    const int nt = (qt * 64 + 64) >> 5;   // kv tiles of 32
    STAGE_T(0, 0);
    for (int t = 0; t < nt; ++t) {
        const int bsel = t & 1;
        const int kv0 = t * 32;
        if (t + 1 < nt) {
            STAGE_T(t + 1, bsel ^ 1);
            WAITV(8);            // tile t landed; t+1's 8 stay in flight
        } else {
            WAITV(0);            // last tile (issued a full phase earlier)
        }
        BAR();

        f32x4 sc[2] = {};
#pragma unroll
        for (int tt = 0; tt < 2; ++tt)
#pragma unroll
            for (int c = 0; c < 8; ++c) {
                int o = (tt * 16 + fr) * 512 + (c * 32 + fo) * 2;
                o ^= (o >> 5) & 0x70;
                short8 kf = *(const short8*)((const char*)Ks[bsel] + o);
                sc[tt] = __builtin_amdgcn_mfma_f32_16x16x32_bf16(qf[c], kf, sc[tt], 0, 0, 0);
            }

        float sv[2][4], pm[4];
#pragma unroll
        for (int j = 0; j < 4; ++j) {
            int qi = qbase + ((lane >> 4) << 2) + j;
#pragma unroll
            for (int tt = 0; tt < 2; ++tt) {
                float x = sc[tt][j] * 0.0625f;
                int kvi = kv0 + tt * 16 + fr;
                sv[tt][j] = (kvi > qi) ? -1e30f : x;
            }
            float p = fmaxf(sv[0][j], sv[1][j]);
#pragma unroll
            for (int off = 1; off < 16; off <<= 1)
                p = fmaxf(p, __shfl_xor(p, off));
            pm[j] = p;
        }
        bool need = (pm[0] > m_run[0] + 8.f) | (pm[1] > m_run[1] + 8.f) |
                    (pm[2] > m_run[2] + 8.f) | (pm[3] > m_run[3] + 8.f);
        if (__any(need)) {
#pragma unroll
            for (int j = 0; j < 4; ++j) {
                float mn = fmaxf(m_run[j], pm[j]);
                float al = __expf(m_run[j] - mn);
                m_run[j] = mn;
                l_run[j] *= al;
#pragma unroll
                for (int n = 0; n < 16; ++n) o_acc[n][j] *= al;
            }
        }
#pragma unroll
        for (int j = 0; j < 4; ++j) {
            float rs = 0.f;
#pragma unroll
            for (int tt = 0; tt < 2; ++tt) {
                float p = __expf(sv[tt][j] - m_run[j]);
                rs += p;
                Ps[wv][(((lane >> 4) << 2) + j) * 32 + tt * 16 + fr] = f2bf(p);
            }
#pragma unroll
            for (int off = 1; off < 16; off <<= 1)
                rs += __shfl_xor(rs, off);
            l_run[j] += rs;
        }

        short8 pf = *(const short8*)&Ps[wv][fr * 32 + fo];
#pragma unroll
        for (int n = 0; n < 16; ++n) {
            int o = (n * 16 + fr) * 64 + fo * 2;
            o ^= (((o >> 6) ^ (o >> 8)) & 3) << 4;
            short8 vf = *(const short8*)((const char*)Vs[bsel] + o);
            o_acc[n] = __builtin_amdgcn_mfma_f32_16x16x32_bf16(pf, vf, o_acc[n], 0, 0, 0);
        }
        BAR();   // retire all reads of buf[bsel] before t+2 stage overwrites
    }

    const int b = bh >> 4, h = bh & 15;
#pragma unroll
    for (int j = 0; j < 4; ++j) {
        float inv = 1.0f / l_run[j];
        int qrow = qbase + ((lane >> 4) << 2) + j;
        size_t base = ((size_t)(b * 2048 + qrow)) * 4096 + h * 256;
#pragma unroll
        for (int n = 0; n < 16; ++n)
            Oa[base + n * 16 + fr] = f2bf(o_acc[n][j] * inv);
    }
}

// ---------- launch ----------
extern "C" void kernel_launch(void* const* d_in, const int* in_sizes, int n_in,
                              void* d_out, int out_size, void* d_ws, size_t ws_size,
                              hipStream_t stream) {
    const float* hidden = (const float*)d_in[0];
    const int* positions = (const int*)d_in[1];
    const float* w_qkv = (const float*)d_in[2];
    const float* w_out = (const float*)d_in[3];
    float* out = (float*)d_out;

    const size_t MB32 = 33554432;   // 32 MiB
    char* ws = (char*)d_ws;
    unsigned short* hidden_bf = (unsigned short*)ws;              // 32 MB; later attn out
    unsigned short* wqkv_bf   = (unsigned short*)(ws + MB32);     // 96 MB; later q/k/vt
    unsigned short* qkv_bf    = (unsigned short*)(ws + 4 * MB32); // 96 MB; later wout_bf
    unsigned short* qp  = wqkv_bf;                                // 32 MB
    unsigned short* kp  = wqkv_bf + 16777216;                     // 32 MB
    unsigned short* vtp = wqkv_bf + 33554432;                     // 32 MB
    unsigned short* attn_bf = hidden_bf;                          // 32 MB (reuse)
    unsigned short* wout_bf = qkv_bf;                             // 32 MB (reuse)

    // 1. convert hidden (16.7M) and w_qkv (50.3M) to bf16
    conv_bf16<<<16384, 256, 0, stream>>>(hidden, hidden_bf, 4194304);
    conv_bf16<<<49152, 256, 0, stream>>>(w_qkv, wqkv_bf, 12582912);

    // 2. qkv = hidden @ w_qkv^T   (M=4096, N=12288, K=4096), bf16 out
    gemm256<true><<<16 * 48, 512, 0, stream>>>(hidden_bf, wqkv_bf, qkv_bf, 4096, 12288, 4096, 48);

    // 3. RoPE + repack q,k ; transpose v
    rope_repack<<<16384, 256, 0, stream>>>(qkv_bf, positions, qp, kp);
    v_transpose<<<4096, 256, 0, stream>>>(qkv_bf, vtp);

    // 4. causal flash attention -> attn_bf [4096, 4096]
    attn_fwd<<<dim3(32, 32), 256, 0, stream>>>(qp, kp, vtp, attn_bf);

    // 5. convert w_out, final projection (fp32 out)
    conv_bf16<<<16384, 256, 0, stream>>>(w_out, wout_bf, 4194304);
    gemm256<false><<<16 * 16, 512, 0, stream>>>(attn_bf, wout_bf, out, 4096, 4096, 4096, 16);
}

// Round 10
// 728.746 us; speedup vs baseline: 1.2083x; 1.2083x over previous
//
#include <hip/hip_runtime.h>

typedef __attribute__((ext_vector_type(8))) short short8;
typedef __attribute__((ext_vector_type(4))) float f32x4;

// ---------- helpers ----------
__device__ __forceinline__ unsigned short f2bf(float f) {
    union { float f; unsigned int u; } v; v.f = f;
    unsigned int u = v.u;
    unsigned int r = (u + 0x7FFFu + ((u >> 16) & 1u)) >> 16;
    return (unsigned short)r;
}
__device__ __forceinline__ float bf2f(unsigned short u) {
    union { unsigned int u; float f; } v; v.u = ((unsigned int)u) << 16;
    return v.f;
}
__device__ __forceinline__ void load_lds16(const void* g, void* l) {
    __builtin_amdgcn_global_load_lds(
        (const __attribute__((address_space(1))) void*)g,
        (__attribute__((address_space(3))) void*)l, 16, 0, 0);
}
#define BAR() asm volatile("s_barrier" ::: "memory")
#define WAITV(n) asm volatile("s_waitcnt vmcnt(" #n ")" ::: "memory")

// LDS swizzle (R3/R4, measured 0 conflicts): XOR row&7 (bits 7-9 at 128B row
// stride) into the 16B-slot index (bits 4-6). Involution on 16B chunks.
__device__ __forceinline__ int swz(int o) { return o ^ ((o >> 3) & 0x70); }

// ---------- fp32 -> bf16 convert ----------
__global__ __launch_bounds__(256) void conv_bf16(const float* __restrict__ in,
                                                 unsigned short* __restrict__ out, int n4) {
    int i = blockIdx.x * 256 + threadIdx.x;
    if (i >= n4) return;
    float4 v = ((const float4*)in)[i];
    ushort4 o;
    o.x = f2bf(v.x); o.y = f2bf(v.y); o.z = f2bf(v.z); o.w = f2bf(v.w);
    ((ushort4*)out)[i] = o;
}

// ---------- 256x256 8-phase GEMM (R4/R8, best measured, 0 conflicts) ----------
template <bool OUT_BF16>
__global__ __launch_bounds__(512, 2) void gemm256(const unsigned short* __restrict__ A,
                                                  const unsigned short* __restrict__ B,
                                                  void* __restrict__ Cv,
                                                  int M, int N, int K, int NBN) {
    __shared__ __align__(16) char smem[131072];
    const int tid = threadIdx.x;
    const int lane = tid & 63, wv = tid >> 6;
    const int wm = wv >> 2, wn = wv & 3;
    const int fr = lane & 15, fo = (lane >> 4) * 8;

    // bijective XCD swizzle (m204)
    const int nwg = gridDim.x, bid = blockIdx.x;
    const int q = nwg >> 3, r = nwg & 7, xcd = bid & 7, lid = bid >> 3;
    const int wg = (xcd < r ? xcd * (q + 1) : r * (q + 1) + (xcd - r) * q) + lid;
    const int bm = wg / NBN, bn = wg % NBN;

    const unsigned short* gA = A + (size_t)bm * 256 * K;
    const unsigned short* gB = B + (size_t)bn * 256 * K;

    // staging geometry: linear LDS dest o -> global element at swz(o)
    int srow[2][2], scol[2][2];
#pragma unroll
    for (int h = 0; h < 2; ++h)
#pragma unroll
        for (int rr = 0; rr < 2; ++rr) {
            int o = h * 16384 + rr * 8192 + tid * 16;
            int osw = swz(o);
            srow[h][rr] = osw >> 7;
            scol[h][rr] = (osw & 127) >> 1;
        }

    f32x4 acc[8][4] = {};
    short8 a[4][2], b[4][2];

    auto STAGE = [&](const unsigned short* g, int regionBase, int h, int t) {
#pragma unroll
        for (int rr = 0; rr < 2; ++rr)
            load_lds16(g + (size_t)srow[h][rr] * K + t * 64 + scol[h][rr],
                       smem + regionBase + h * 16384 + rr * 8192 + tid * 16);
    };
    auto RDA = [&](int bufBase, int mh) {
#pragma unroll
        for (int mf = 0; mf < 4; ++mf)
#pragma unroll
            for (int ks = 0; ks < 2; ++ks) {
                int o = swz((wm * 128 + mh * 64 + mf * 16 + fr) * 128 + (ks * 32 + fo) * 2);
                a[mf][ks] = *(const short8*)(smem + bufBase + o);
            }
    };
    auto RDB = [&](int bufBase, int nh) {
#pragma unroll
        for (int jj = 0; jj < 2; ++jj)
#pragma unroll
            for (int ks = 0; ks < 2; ++ks) {
                int o = swz((wn * 64 + (nh * 2 + jj) * 16 + fr) * 128 + (ks * 32 + fo) * 2);
                b[nh * 2 + jj][ks] = *(const short8*)(smem + bufBase + 32768 + o);
            }
    };
    auto MM = [&](int mh, int nh) {
        __builtin_amdgcn_s_setprio(1);
#pragma unroll
        for (int mf = 0; mf < 4; ++mf)
#pragma unroll
            for (int jj = 0; jj < 2; ++jj)
#pragma unroll
                for (int ks = 0; ks < 2; ++ks)
                    acc[mh * 4 + mf][nh * 2 + jj] = __builtin_amdgcn_mfma_f32_16x16x32_bf16(
                        a[mf][ks], b[nh * 2 + jj][ks], acc[mh * 4 + mf][nh * 2 + jj], 0, 0, 0);
        __builtin_amdgcn_s_setprio(0);
    };

    const int A0 = 0, B0 = 32768, A1 = 65536, B1 = 98304;

    // prologue: t0 (A,B) -> buf0; t1 (B,A) -> buf1. 16 loads.
    STAGE(gA, A0, 0, 0); STAGE(gA, A0, 1, 0);
    STAGE(gB, B0, 0, 0); STAGE(gB, B0, 1, 0);
    STAGE(gB, B1, 0, 1); STAGE(gB, B1, 1, 1);
    STAGE(gA, A1, 0, 1); STAGE(gA, A1, 1, 1);
    WAITV(8);
    BAR();
    RDA(A0, 0);
    RDB(A0, 0);

    const int NIT = K >> 7;  // K/128
    for (int i = 0; i < NIT; ++i) {
        const bool last = (i == NIT - 1);
        const int t2 = 2 * i + 2, t3 = 2 * i + 3;
        // P1
        RDB(A0, 1);
        MM(0, 0);
        if (i > 0) STAGE(gA, A1, 1, 2 * i + 1);
        BAR();
        // P2
        MM(0, 1);
        RDA(A0, 1);
        BAR();
        // P3
        MM(1, 1);
        if (!last) {
            STAGE(gB, B0, 0, t2);
            WAITV(2);
        } else {
            WAITV(0);
        }
        BAR();
        // P4
        MM(1, 0);
        RDA(A1, 0); RDB(A1, 0);
        if (!last) { STAGE(gB, B0, 1, t2); STAGE(gA, A0, 0, t2); }
        BAR();
        // P5
        RDB(A1, 1);
        MM(0, 0);
        if (!last) STAGE(gA, A0, 1, t2);
        BAR();
        // P6
        MM(0, 1);
        RDA(A1, 1);
        BAR();
        // P7
        MM(1, 1);
        if (!last) {
            STAGE(gB, B1, 0, t3);
            WAITV(2);
        }
        BAR();
        // P8
        MM(1, 0);
        if (!last) {
            RDA(A0, 0); RDB(A0, 0);
            STAGE(gB, B1, 1, t3); STAGE(gA, A1, 0, t3);
        }
        BAR();
    }

    // epilogue
    const size_t row0 = (size_t)bm * 256 + wm * 128 + ((lane >> 4) << 2);
    const int col0 = bn * 256 + wn * 64 + fr;
#pragma unroll
    for (int mf = 0; mf < 8; ++mf)
#pragma unroll
        for (int nf = 0; nf < 4; ++nf)
#pragma unroll
            for (int j = 0; j < 4; ++j) {
                size_t idx = (row0 + mf * 16 + j) * (size_t)N + col0 + nf * 16;
                if (OUT_BF16) ((unsigned short*)Cv)[idx] = f2bf(acc[mf][nf][j]);
                else          ((float*)Cv)[idx] = acc[mf][nf][j];
            }
}

// ---------- RoPE (interleaved, first 64 dims) + repack q,k -> [b,h,s,d] ----------
__global__ __launch_bounds__(256) void rope_repack(const unsigned short* __restrict__ qkv,
                                                   const int* __restrict__ positions,
                                                   unsigned short* __restrict__ qp,
                                                   unsigned short* __restrict__ kp) {
    int r = blockIdx.x * 4 + (threadIdx.x >> 6);   // (b,s,h) row, 0..65535
    int h = r & 15, s = (r >> 4) & 2047, b = r >> 15;
    int d = (threadIdx.x & 63) * 4;
    const unsigned short* src = qkv + (size_t)(b * 2048 + s) * 12288 + h * 256 + d;
    ushort4 q = *(const ushort4*)src;
    ushort4 k = *(const ushort4*)(src + 4096);
    if (d < 64) {
        float pos = (float)positions[s];
        const float LF = 0.4152410118609203f;      // log2(10000)/32
        float i0 = (float)(d >> 1);
        float a0 = pos * exp2f(-i0 * LF);
        float a1 = pos * exp2f(-(i0 + 1.0f) * LF);
        float c0 = cosf(a0), s0 = sinf(a0), c1 = cosf(a1), s1 = sinf(a1);
        float qx = bf2f(q.x), qy = bf2f(q.y), qz = bf2f(q.z), qw = bf2f(q.w);
        q.x = f2bf(qx * c0 - qy * s0); q.y = f2bf(qx * s0 + qy * c0);
        q.z = f2bf(qz * c1 - qw * s1); q.w = f2bf(qz * s1 + qw * c1);
        float kx = bf2f(k.x), ky = bf2f(k.y), kz = bf2f(k.z), kw = bf2f(k.w);
        k.x = f2bf(kx * c0 - ky * s0); k.y = f2bf(kx * s0 + ky * c0);
        k.z = f2bf(kz * c1 - kw * s1); k.w = f2bf(kz * s1 + kw * c1);
    }
    size_t dst = ((size_t)((b * 16 + h) * 2048 + s)) * 256 + d;
    *(ushort4*)&qp[dst] = q;
    *(ushort4*)&kp[dst] = k;
}

// ---------- V transpose -> [b,h,d,s] ----------
__global__ __launch_bounds__(256) void v_transpose(const unsigned short* __restrict__ qkv,
                                                   unsigned short* __restrict__ vt) {
    int bid = blockIdx.x;
    int dt = bid & 3, st = (bid >> 2) & 31, bh = bid >> 7;
    int b = bh >> 4, h = bh & 15;
    __shared__ unsigned short t[64][72];
    int tid = threadIdx.x;
#pragma unroll
    for (int rep = 0; rep < 16; ++rep) {
        int idx = rep * 256 + tid;
        int r = idx >> 6, c = idx & 63;   // r: s-offset, c: d-offset
        t[r][c] = qkv[(size_t)(b * 2048 + st * 64 + r) * 12288 + 8192 + h * 256 + dt * 64 + c];
    }
    __syncthreads();
#pragma unroll
    for (int rep = 0; rep < 16; ++rep) {
        int idx = rep * 256 + tid;
        int r = idx >> 6, c = idx & 63;   // r: d-offset, c: s-offset
        vt[(size_t)(bh * 256 + dt * 64 + r) * 2048 + st * 64 + c] = t[c][r];
    }
}

// ---------- flash attention (causal), 4 waves x 16 q-rows, KV tile 32 ----------
// SWAPPED QK^T (R10): sc = mfma(K, Q) -> D col = q = lane&15 (fr), row =
// kv = (lane>>4)*4+j. Softmax row-reduce is 7 in-lane ops + 2 shfl_xor
// (16,32) instead of 32 shfls/tile. m_run/l_run are per-lane scalars in
// q=fr layout; alpha / 1/l are redistributed to the PV layout (q=g*4+j)
// with 4 shfls only when defer-max fires / at epilogue.
// P stored transposed [q][kv], row stride 80 B (odd 16B multiple -> banks
// spread; write = 2 x ds_write_b64/lane, read = 1 x b128 16B-aligned).
// K/V staging + swizzles + defer-max(THR=8) unchanged from R8 (verified).
// LDS: 16K + 16K + 5K = 37 KB -> 4 blocks/CU (R9 dbuf reverted: occupancy
// loss outweighed latency hiding).
__global__ __launch_bounds__(256) void attn_fwd(const unsigned short* __restrict__ Qp,
                                                const unsigned short* __restrict__ Kp,
                                                const unsigned short* __restrict__ Vt,
                                                unsigned short* __restrict__ Oa) {
    __shared__ __align__(16) unsigned short Ks[32 * 256];
    __shared__ __align__(16) unsigned short Vs[256 * 32];
    __shared__ __align__(16) char Ps[4 * 16 * 80];
    const int tid = threadIdx.x, lane = tid & 63, wv = tid >> 6;
    const int bh = blockIdx.x, qt = blockIdx.y;
    const int fr = lane & 15, g = lane >> 4, fo = g * 8;
    const unsigned short* Qb = Qp + (size_t)bh * 2048 * 256;
    const unsigned short* Kb = Kp + (size_t)bh * 2048 * 256;
    const unsigned short* Vb = Vt + (size_t)bh * 256 * 2048;
    const int qbase = qt * 64 + wv * 16;
    char* PsW = Ps + wv * 1280;

    short8 qf[8];
#pragma unroll
    for (int c = 0; c < 8; ++c)
        qf[c] = *(const short8*)&Qb[(size_t)(qbase + fr) * 256 + c * 32 + fo];

    f32x4 o_acc[16] = {};
    float m_run = -1e30f, l_run = 0.f;
    const int qi = qbase + fr;

    const int nkv = qt * 64 + 64;
    for (int kv0 = 0; kv0 < nkv; kv0 += 32) {
        // stage K tile [32][256] swizzled (R8)
#pragma unroll
        for (int i = 0; i < 4; ++i) {
            int ob = (wv * 4 + i) * 1024 + lane * 16;
            int osw = ob ^ ((ob >> 5) & 0x70);
            int row = kv0 + (ob >> 9);
            load_lds16(&Kb[(size_t)row * 256 + ((osw & 511) >> 1)],
                       (char*)Ks + (wv * 4 + i) * 1024);
        }
        // stage V^T tile [256][32] swizzled (R8)
#pragma unroll
        for (int i = 0; i < 4; ++i) {
            int ob = (wv * 4 + i) * 1024 + lane * 16;
            int osw = ob ^ ((((ob >> 6) ^ (ob >> 8)) & 3) << 4);
            int drow = ob >> 6;
            load_lds16(&Vb[(size_t)drow * 2048 + kv0 + ((osw & 63) >> 1)],
                       (char*)Vs + (wv * 4 + i) * 1024);
        }
        __syncthreads();

        // QK^T swapped: D row = kv = g*4+j (+16tt), col = q = fr
        f32x4 sc[2] = {};
#pragma unroll
        for (int tt = 0; tt < 2; ++tt)
#pragma unroll
            for (int c = 0; c < 8; ++c) {
                int o = (tt * 16 + fr) * 512 + (c * 32 + fo) * 2;
                o ^= (o >> 5) & 0x70;
                short8 kf = *(const short8*)((const char*)Ks + o);
                sc[tt] = __builtin_amdgcn_mfma_f32_16x16x32_bf16(kf, qf[c], sc[tt], 0, 0, 0);
            }

        // mask + in-lane row max (q = fr owns all 8 slots)
        float sv[2][4];
        float pmax = -1e30f;
#pragma unroll
        for (int tt = 0; tt < 2; ++tt)
#pragma unroll
            for (int j = 0; j < 4; ++j) {
                int kvi = kv0 + tt * 16 + g * 4 + j;
                float x = sc[tt][j] * 0.0625f;
                sv[tt][j] = (kvi > qi) ? -1e30f : x;
                pmax = fmaxf(pmax, sv[tt][j]);
            }
        pmax = fmaxf(pmax, __shfl_xor(pmax, 16));
        pmax = fmaxf(pmax, __shfl_xor(pmax, 32));

        // defer-max rescale (rare)
        if (__any(pmax > m_run + 8.f)) {
            float mn = fmaxf(m_run, pmax);
            float al = __expf(m_run - mn);
            m_run = mn;
            l_run *= al;
            float alj[4];
#pragma unroll
            for (int j = 0; j < 4; ++j) alj[j] = __shfl(al, g * 4 + j);
#pragma unroll
            for (int n = 0; n < 16; ++n) {
                o_acc[n][0] *= alj[0]; o_acc[n][1] *= alj[1];
                o_acc[n][2] *= alj[2]; o_acc[n][3] *= alj[3];
            }
        }

        // P = exp(sv - m), packed transposed store Ps[q=fr][kv]
        float rs = 0.f;
#pragma unroll
        for (int tt = 0; tt < 2; ++tt) {
            float p0 = __expf(sv[tt][0] - m_run);
            float p1 = __expf(sv[tt][1] - m_run);
            float p2 = __expf(sv[tt][2] - m_run);
            float p3 = __expf(sv[tt][3] - m_run);
            rs += (p0 + p1) + (p2 + p3);
            ushort4 pk;
            pk.x = f2bf(p0); pk.y = f2bf(p1); pk.z = f2bf(p2); pk.w = f2bf(p3);
            *(ushort4*)(PsW + fr * 80 + tt * 32 + g * 8) = pk;
        }
        rs += __shfl_xor(rs, 16);
        rs += __shfl_xor(rs, 32);
        l_run += rs;

        // PV: pf = P^T[q=fr][kv=fo..fo+7] (16B aligned: 80 = 5*16)
        short8 pf = *(const short8*)(PsW + fr * 80 + g * 16);
#pragma unroll
        for (int n = 0; n < 16; ++n) {
            int o = (n * 16 + fr) * 64 + fo * 2;
            o ^= (((o >> 6) ^ (o >> 8)) & 3) << 4;
            short8 vf = *(const short8*)((const char*)Vs + o);
            o_acc[n] = __builtin_amdgcn_mfma_f32_16x16x32_bf16(pf, vf, o_acc[n], 0, 0, 0);
        }
        __syncthreads();
    }

    // epilogue: o_acc row q = g*4+j, col d = n*16+fr; 1/l from fr-layout
    const int b = bh >> 4, h = bh & 15;
    float linv = 1.0f / l_run;
#pragma unroll
    for (int j = 0; j < 4; ++j) {
        float inv = __shfl(linv, g * 4 + j);
        int qrow = qbase + g * 4 + j;
        size_t base = ((size_t)(b * 2048 + qrow)) * 4096 + h * 256;
#pragma unroll
        for (int n = 0; n < 16; ++n)
            Oa[base + n * 16 + fr] = f2bf(o_acc[n][j] * inv);
    }
}

// ---------- launch ----------
extern "C" void kernel_launch(void* const* d_in, const int* in_sizes, int n_in,
                              void* d_out, int out_size, void* d_ws, size_t ws_size,
                              hipStream_t stream) {
    const float* hidden = (const float*)d_in[0];
    const int* positions = (const int*)d_in[1];
    const float* w_qkv = (const float*)d_in[2];
    const float* w_out = (const float*)d_in[3];
    float* out = (float*)d_out;

    const size_t MB32 = 33554432;   // 32 MiB
    char* ws = (char*)d_ws;
    unsigned short* hidden_bf = (unsigned short*)ws;              // 32 MB; later attn out
    unsigned short* wqkv_bf   = (unsigned short*)(ws + MB32);     // 96 MB; later q/k/vt
    unsigned short* qkv_bf    = (unsigned short*)(ws + 4 * MB32); // 96 MB; later wout_bf
    unsigned short* qp  = wqkv_bf;                                // 32 MB
    unsigned short* kp  = wqkv_bf + 16777216;                     // 32 MB
    unsigned short* vtp = wqkv_bf + 33554432;                     // 32 MB
    unsigned short* attn_bf = hidden_bf;                          // 32 MB (reuse)
    unsigned short* wout_bf = qkv_bf;                             // 32 MB (reuse)

    // 1. convert hidden (16.7M) and w_qkv (50.3M) to bf16
    conv_bf16<<<16384, 256, 0, stream>>>(hidden, hidden_bf, 4194304);
    conv_bf16<<<49152, 256, 0, stream>>>(w_qkv, wqkv_bf, 12582912);

    // 2. qkv = hidden @ w_qkv^T   (M=4096, N=12288, K=4096), bf16 out
    gemm256<true><<<16 * 48, 512, 0, stream>>>(hidden_bf, wqkv_bf, qkv_bf, 4096, 12288, 4096, 48);

    // 3. RoPE + repack q,k ; transpose v
    rope_repack<<<16384, 256, 0, stream>>>(qkv_bf, positions, qp, kp);
    v_transpose<<<4096, 256, 0, stream>>>(qkv_bf, vtp);

    // 4. causal flash attention -> attn_bf [4096, 4096]
    attn_fwd<<<dim3(32, 32), 256, 0, stream>>>(qp, kp, vtp, attn_bf);

    // 5. convert w_out, final projection (fp32 out)
    conv_bf16<<<16384, 256, 0, stream>>>(w_out, wout_bf, 4194304);
    gemm256<false><<<16 * 16, 512, 0, stream>>>(attn_bf, wout_bf, out, 4096, 4096, 4096, 16);
}